// Round 4
// baseline (285.238 us; speedup 1.0000x reference)
//
#include <hip/hip_runtime.h>
#include <cstddef>

// Problem constants (match reference)
constexpr int Bn = 2048;
constexpr int Dn = 512;
// Chain hypothesis R4: SINGLE sequential fma chain k=0..511 per element:
//   adc[i][j] = fl32( fl32(sum_fma) / 0.07f )
// (BLIS zen KC>=512 / kc>=K BLAS / plain C loop with fp-contract). Tested and
// falsified so far: fp64-exact (R1), 384+128 (R2), 256+256 (R3).
// Remaining fallbacks: 192+160+160, unfused mul+add single chain,
// fp32 matmul + fp64 divide/subtract promotion.

// ---------------- workspace control block ----------------
struct Ctl {
  unsigned hist1[4096];   // key bits [31:20]
  unsigned hist2[4096];   // key bits [19:8]  within b1
  unsigned hist3[256];    // key bits [7:0]   within (b1,b2)
  unsigned n_neg, k;
  int      b1, b2;
  unsigned above1, above2;
  float    thrF;
  unsigned singles;
  double   lossSum;
};

// Monotone fp32 -> uint32 key (larger float => larger key)
__device__ inline unsigned key_of(float L) {
  unsigned u = __float_as_uint(L);
  return (u & 0x80000000u) ? ~u : (u | 0x80000000u);
}

// ---------------- fp32 Gram matrix, single sequential FMA chain ----------------
// 64x64 tile / 256 threads / 4x4 microtile / k-chunks of 16.
__global__ __launch_bounds__(256) void gemm_adc(const float* __restrict__ F,
                                                float* __restrict__ adc) {
  __shared__ float As[16][65];
  __shared__ float Bs[16][65];
  const int t  = threadIdx.x;
  const int tx = t & 15, ty = t >> 4;
  const int lr = t >> 2, lq = t & 3;   // loader: row, float4-quad
  const int i0 = blockIdx.y * 64, j0 = blockIdx.x * 64;

  float acc[4][4] = {};

  for (int k0 = 0; k0 < Dn; k0 += 16) {
    float4 av = *(const float4*)(F + (size_t)(i0 + lr) * Dn + k0 + lq * 4);
    float4 bv = *(const float4*)(F + (size_t)(j0 + lr) * Dn + k0 + lq * 4);
    __syncthreads();   // protect LDS from previous iteration's readers
    As[lq * 4 + 0][lr] = av.x; As[lq * 4 + 1][lr] = av.y;
    As[lq * 4 + 2][lr] = av.z; As[lq * 4 + 3][lr] = av.w;
    Bs[lq * 4 + 0][lr] = bv.x; Bs[lq * 4 + 1][lr] = bv.y;
    Bs[lq * 4 + 2][lr] = bv.z; Bs[lq * 4 + 3][lr] = bv.w;
    __syncthreads();
#pragma unroll
    for (int k = 0; k < 16; ++k) {
      float a[4], b[4];
#pragma unroll
      for (int m = 0; m < 4; ++m) a[m] = As[k][ty + 16 * m];
#pragma unroll
      for (int n = 0; n < 4; ++n) b[n] = Bs[k][tx + 16 * n];
#pragma unroll
      for (int m = 0; m < 4; ++m)
#pragma unroll
        for (int n = 0; n < 4; ++n)
          acc[m][n] = __builtin_fmaf(a[m], b[n], acc[m][n]);  // strict k-order chain
    }
  }
#pragma unroll
  for (int m = 0; m < 4; ++m)
#pragma unroll
    for (int n = 0; n < 4; ++n) {
      float v = acc[m][n] / 0.07f;   // IEEE fp32 div
      adc[(size_t)(i0 + ty + 16 * m) * Bn + (j0 + tx + 16 * n)] = v;
    }
}

// ---------------- per-row max (exact fp32 max) ----------------
__global__ __launch_bounds__(256) void rowmax_k(const float* __restrict__ adc,
                                                float* __restrict__ rowmax) {
  const int i = blockIdx.x;
  float m = __int_as_float(0xff800000);  // -inf
  for (int j = threadIdx.x; j < Bn; j += 256)
    m = fmaxf(m, adc[(size_t)i * Bn + j]);
#pragma unroll
  for (int o = 32; o > 0; o >>= 1) m = fmaxf(m, __shfl_down(m, o, 64));
  __shared__ float s[4];
  const int lane = threadIdx.x & 63, w = threadIdx.x >> 6;
  if (lane == 0) s[w] = m;
  __syncthreads();
  if (threadIdx.x == 0) rowmax[i] = fmaxf(fmaxf(s[0], s[1]), fmaxf(s[2], s[3]));
}

// ---------------- radix histogram passes on exact fp32 bit patterns ----------------
// pass 1: bits[31:20] + n_neg count; pass 2: bits[19:8] within b1;
// pass 3: bits[7:0] within (b1,b2).
__global__ __launch_bounds__(256) void hist_k(const float* __restrict__ adc,
                                              const float* __restrict__ rowmax,
                                              const int* __restrict__ labels,
                                              Ctl* c, int pass) {
  __shared__ unsigned h[4096];
  __shared__ int slab[Bn];
  __shared__ unsigned negc;
  const int NH = (pass == 3) ? 256 : 4096;
  unsigned b1 = 0, pre2 = 0;
  if (pass == 2) b1 = (unsigned)c->b1;
  if (pass == 3) pre2 = (((unsigned)c->b1) << 12) | (unsigned)c->b2;
  for (int q = threadIdx.x; q < NH; q += 256) h[q] = 0;
  for (int j = threadIdx.x; j < Bn; j += 256) slab[j] = labels[j];
  if (threadIdx.x == 0) negc = 0;
  __syncthreads();
  unsigned myneg = 0;
  for (int rr = 0; rr < 8; ++rr) {
    const int i = blockIdx.x * 8 + rr;
    const int li = slab[i];
    const float rm = rowmax[i];
    for (int j = threadIdx.x; j < Bn; j += 256) {
      if (j == i || slab[j] == li) continue;
      const float L = adc[(size_t)i * Bn + j] - rm;   // exact fp32 sub, same everywhere
      const unsigned key = key_of(L);
      if (pass == 1) {
        atomicAdd(&h[key >> 20], 1u); ++myneg;
      } else if (pass == 2) {
        if ((key >> 20) == b1) atomicAdd(&h[(key >> 8) & 0xFFFu], 1u);
      } else {
        if ((key >> 8) == pre2) atomicAdd(&h[key & 0xFFu], 1u);
      }
    }
  }
  if (pass == 1) atomicAdd(&negc, myneg);
  __syncthreads();
  unsigned* dst = (pass == 1) ? c->hist1 : (pass == 2) ? c->hist2 : c->hist3;
  for (int q = threadIdx.x; q < NH; q += 256)
    if (h[q]) atomicAdd(&dst[q], h[q]);
  if (pass == 1 && threadIdx.x == 0) atomicAdd(&c->n_neg, negc);
}

// ---------------- bucket selection (suffix scan from the top) ----------------
__global__ __launch_bounds__(256) void select_k(Ctl* c, int pass) {
  __shared__ unsigned tsum[256];
  __shared__ unsigned suffix[256];
  __shared__ unsigned kk, base;
  const int t = threadIdx.x;
  if (t == 0) {
    if (pass == 1) {
      unsigned k = c->n_neg >> 1;   // floor(0.5*n_neg), exact vs ref
      if (k < 1) k = 1;
      c->k = k; kk = k; base = 0;
    } else if (pass == 2) { kk = c->k; base = c->above1; }
    else                  { kk = c->k; base = c->above2; }
  }
  __syncthreads();
  const unsigned* hist = (pass == 1) ? c->hist1 : (pass == 2) ? c->hist2 : c->hist3;
  const int U = (pass == 3) ? 1 : 16;
  unsigned hv[16];
  unsigned s = 0;
  for (int u = 0; u < U; ++u) { hv[u] = hist[t * U + u]; s += hv[u]; }
  tsum[t] = s;
  __syncthreads();
  if (t == 0) {
    unsigned acc = base;
    for (int q = 255; q >= 0; --q) { suffix[q] = acc; acc += tsum[q]; }
  }
  __syncthreads();
  unsigned cum = suffix[t];  // count strictly above this thread's top bucket
  for (int u = U - 1; u >= 0; --u) {
    if (cum < kk && cum + hv[u] >= kk) {
      const int b = t * U + u;
      if (pass == 1)      { c->b1 = b; c->above1 = cum; }
      else if (pass == 2) { c->b2 = b; c->above2 = cum; }
      else {
        const unsigned key = ((unsigned)c->b1 << 20) | ((unsigned)c->b2 << 8) | (unsigned)b;
        c->thrF = __uint_as_float((key & 0x80000000u) ? (key ^ 0x80000000u) : ~key);
      }
    }
    cum += hv[u];
  }
}

__device__ inline double block_sum(double v) {
  __shared__ double s[4];
#pragma unroll
  for (int o = 32; o > 0; o >>= 1) v += __shfl_down(v, o, 64);
  const int lane = threadIdx.x & 63, w = threadIdx.x >> 6;
  __syncthreads();
  if (lane == 0) s[w] = v;
  __syncthreads();
  return s[0] + s[1] + s[2] + s[3];
}

// ---------------- fused mask + loss pass, one block per row ----------------
__global__ __launch_bounds__(256) void final_k(const float* __restrict__ adc,
                                               const float* __restrict__ rowmax,
                                               const int* __restrict__ labels,
                                               Ctl* c, float* __restrict__ out) {
  __shared__ int slab[Bn];
  const int i = blockIdx.x;
  for (int j = threadIdx.x; j < Bn; j += 256) slab[j] = labels[j];
  __syncthreads();
  const int li = slab[i];
  const float rm = rowmax[i];
  const float thr = c->thrF;
  float* __restrict__ ohnm = out + 1;
  float* __restrict__ ofin = out + 1 + (size_t)Bn * Bn;

  double sumexp = 0.0, spos = 0.0;
  int pcnt = 0;
  for (int j = threadIdx.x; j < Bn; j += 256) {
    const float L = adc[(size_t)i * Bn + j] - rm;   // identical fp32 value as hist passes
    const bool offd = (j != i);
    const bool same = (slab[j] == li);
    const bool neg  = offd && !same;
    const bool hnm  = neg && (L >= thr);            // exact fp32 compare
    const bool fin  = offd && (same || hnm);
    if (offd) sumexp += exp((double)L);
    if (fin)  { spos += (double)L; ++pcnt; }
    ohnm[(size_t)i * Bn + j] = hnm ? 1.0f : 0.0f;
    ofin[(size_t)i * Bn + j] = fin ? 1.0f : 0.0f;
  }
  sumexp = block_sum(sumexp);
  spos   = block_sum(spos);
  double pc = block_sum((double)pcnt);
  if (threadIdx.x == 0) {
    const double P = pc;
    const bool single = (P == 0.0);
    const double mlpp = (spos - P * log(sumexp + 1e-12)) / (P + (single ? 1.0 : 0.0));
    const double lv = single ? 0.0 : -mlpp;
    atomicAdd(&c->lossSum, lv);
    if (single) atomicAdd(&c->singles, 1u);
  }
}

__global__ void finalize_k(const Ctl* c, float* out) {
  out[0] = (float)(c->lossSum / ((double)Bn - (double)c->singles));
}

// ---------------- launch ----------------
extern "C" void kernel_launch(void* const* d_in, const int* in_sizes, int n_in,
                              void* d_out, int out_size, void* d_ws, size_t ws_size,
                              hipStream_t stream) {
  const float* F      = (const float*)d_in[0];
  const int*   labels = (const int*)d_in[1];
  float* out = (float*)d_out;

  char* ws = (char*)d_ws;
  float* adc    = (float*)ws;                                   // 2048*2048*4 = 16.78 MB
  float* rowmax = (float*)(ws + (size_t)Bn * Bn * 4);           // 8 KB
  Ctl*   c      = (Ctl*)(ws + (size_t)Bn * Bn * 4 + (size_t)Bn * 4);

  hipMemsetAsync(c, 0, sizeof(Ctl), stream);

  gemm_adc<<<dim3(Bn / 64, Bn / 64), 256, 0, stream>>>(F, adc);
  rowmax_k<<<Bn, 256, 0, stream>>>(adc, rowmax);
  hist_k<<<Bn / 8, 256, 0, stream>>>(adc, rowmax, labels, c, 1);
  select_k<<<1, 256, 0, stream>>>(c, 1);
  hist_k<<<Bn / 8, 256, 0, stream>>>(adc, rowmax, labels, c, 2);
  select_k<<<1, 256, 0, stream>>>(c, 2);
  hist_k<<<Bn / 8, 256, 0, stream>>>(adc, rowmax, labels, c, 3);
  select_k<<<1, 256, 0, stream>>>(c, 3);
  final_k<<<Bn, 256, 0, stream>>>(adc, rowmax, labels, c, out);
  finalize_k<<<1, 1, 0, stream>>>(c, out);
}